// Round 15
// baseline (421.744 us; speedup 1.0000x reference)
//
#include <hip/hip_runtime.h>
#include <hip/hip_bf16.h>
#include <cstdio>

#define B_    64
#define L_    512
#define DIN   256
#define DPOS  64
#define DD    320
#define HH    8
#define ROWS  (B_*L_)     // 32768
#define NQKV  1536

typedef __attribute__((ext_vector_type(4))) float floatx4;
typedef __attribute__((ext_vector_type(8))) __bf16 bf16x8;
typedef __attribute__((ext_vector_type(4))) __bf16 bf16x4;

static __device__ __forceinline__ floatx4 mfma_bf16(bf16x8 a, bf16x8 b, floatx4 c) {
  return __builtin_amdgcn_mfma_f32_16x16x32_bf16(a, b, c, 0, 0, 0);
}

#define GLOAD_LDS(gp, lp) \
  __builtin_amdgcn_global_load_lds((const __attribute__((address_space(1))) void*)(gp), \
                                   (__attribute__((address_space(3))) void*)(lp), 16, 0, 0)

// ---------------- prep_all: sort + counter-zero | weight transpose | X convert (one launch) ----------------
// Grid = 1 + 168 + 10240. Block 0: argsort(lengths) desc + zero finalize counters.
// Blocks 1..168: one 64x64 W tile each. Blocks 169+: X = concat(emb,boxes) -> bf16.
__global__ __launch_bounds__(256)
void prep_all(const float* __restrict__ emb, const float* __restrict__ boxes,
              __hip_bfloat16* __restrict__ X,
              const float* __restrict__ Wq, const float* __restrict__ Wk,
              const float* __restrict__ Wv, const float* __restrict__ W1,
              const float* __restrict__ W2,
              __hip_bfloat16* __restrict__ WqkvT, __hip_bfloat16* __restrict__ W1T,
              __hip_bfloat16* __restrict__ W2T,
              const int* __restrict__ len, int* __restrict__ order,
              int* __restrict__ counters) {
  __shared__ float tile[64][65];
  int blk = blockIdx.x, t = threadIdx.x;
  if (blk == 0) {
    if (t < 64) {
      int lb = len[t];
      int rank = 0;
      for (int j = 0; j < 64; ++j) {
        int lj = len[j];
        if (lj > lb || (lj == lb && j < t)) ++rank;
      }
      order[rank] = t;
    }
    if (t < 2) counters[t] = 0;
    return;
  }
  if (blk <= 168) {
    int wb = blk - 1;
    const float* src; __hip_bfloat16* dst; int n0, k0, ldsrc, lddst;
    if (wb < 120) {
      int m = wb / 40, rel = wb % 40;
      src = (m == 0) ? Wq : (m == 1) ? Wk : Wv;
      dst = WqkvT + (size_t)m * 512 * DD;
      n0 = (rel / 5) * 64; k0 = (rel % 5) * 64; ldsrc = 512; lddst = DD;
    } else if (wb < 152) {
      int rel = wb - 120;
      src = W1; dst = W1T; n0 = (rel >> 3) * 64; k0 = (rel & 7) * 64; ldsrc = 256; lddst = 512;
    } else {
      int rel = wb - 152;
      src = W2; dst = W2T; n0 = (rel >> 2) * 64; k0 = (rel & 3) * 64; ldsrc = 256; lddst = 256;
    }
#pragma unroll
    for (int i = 0; i < 16; ++i) {
      int e = i * 256 + t, kr = e >> 6, nc = e & 63;
      tile[kr][nc] = src[(size_t)(k0 + kr) * ldsrc + n0 + nc];
    }
    __syncthreads();
#pragma unroll
    for (int i = 0; i < 4; ++i) {
      int ww = i * 256 + t, nr = ww >> 4, kc = (ww & 15) * 4;
      bf16x4 o;
      o[0] = (__bf16)tile[kc][nr];   o[1] = (__bf16)tile[kc+1][nr];
      o[2] = (__bf16)tile[kc+2][nr]; o[3] = (__bf16)tile[kc+3][nr];
      *(bf16x4*)(dst + (size_t)(n0 + nr) * lddst + k0 + kc) = o;
    }
    return;
  }
  int bb = blk - 169;
  if (bb < ROWS/4) {
    int idx = bb * 256 + t;                      // ROWS*64 threads, 4 f32 each
    int row = idx >> 6, c4 = (idx & 63) * 4;
    const float4 v = *(const float4*)(emb + (size_t)idx * 4);
    bf16x4 o; o[0] = (__bf16)v.x; o[1] = (__bf16)v.y; o[2] = (__bf16)v.z; o[3] = (__bf16)v.w;
    *(bf16x4*)((__bf16*)X + (size_t)row * DD + c4) = o;
  } else {
    int idx = (bb - ROWS/4) * 256 + t;           // ROWS*16 threads
    int row = idx >> 4, c4 = (idx & 15) * 4;
    const float4 v = *(const float4*)(boxes + (size_t)idx * 4);
    bf16x4 o; o[0] = (__bf16)v.x; o[1] = (__bf16)v.y; o[2] = (__bf16)v.z; o[3] = (__bf16)v.w;
    *(bf16x4*)((__bf16*)X + (size_t)row * DD + DIN + c4) = o;
  }
}

// ---------------- GEMM v12: 128x128 tile, BK=64 dbuf, 512 threads, fused BN finalize ----------------
// LPT via order[] (XCD-striped). M-sparse skip. M = 32768 (256 by-blocks).
// EPI 0: QKV split (bf16): n0<1024 -> QK; else VT[b,h,v,l] via LDS transpose.
// EPI 1: bf16 out + bias; masked BN partials -> pS/pS2; LAST block (atomic counter)
//        reduces partials and writes aff[] in-kernel (saves stats_fin launches).
template<int EPI>
__global__ __launch_bounds__(512)
void gemm_bt(const __hip_bfloat16* __restrict__ A, const __hip_bfloat16* __restrict__ BT,
             int nbx, int N, int K, int lda,
             const float* __restrict__ bias,
             __hip_bfloat16* __restrict__ outQK, __hip_bfloat16* __restrict__ outVT,
             const int* __restrict__ lengths, const int* __restrict__ order,
             float* __restrict__ pS, float* __restrict__ pS2,
             const float* __restrict__ g, const float* __restrict__ be,
             float* __restrict__ aff, int* __restrict__ cnt) {
  __shared__ __align__(16) __bf16 sm[32768];  // 64 KB: A0 A1 | B0 B1 (8192 elems each)
  __shared__ int islast;
  int hw = blockIdx.x;
  int lidx = (hw & 7) * ((int)gridDim.x >> 3) + (hw >> 3);
  int bx = lidx % nbx, by = lidx / nbx;       // by in [0,256)
  int t = threadIdx.x;
  int brank = ((by & 31) >> 2) * 8 + (by >> 5);
  int bb = order[brank];
  int m0 = bb * 512 + (by & 3) * 128;
  int n0 = bx * 128;
  int lenb = lengths[bb];
  bool skip = (m0 & 511) >= lenb;

  if (!skip) {
    int wave = t >> 6, lane = t & 63, lr = lane & 15, lg = lane >> 4;
    int wr = wave >> 1, wc = wave & 1;   // wr: 32 rows each; wc: 64 cols each
    floatx4 acc[2][4];
#pragma unroll
    for (int i = 0; i < 2; ++i)
#pragma unroll
      for (int j = 0; j < 4; ++j)
#pragma unroll
        for (int q = 0; q < 4; ++q) acc[i][j][q] = 0.f;

    int srow = t >> 3;
    int scb = (t & 7) ^ (srow & 7);
    const __bf16* gA = (const __bf16*)A + (size_t)(m0 + srow) * lda + scb * 8;
    const __bf16* gB = (const __bf16*)BT + (size_t)(n0 + srow) * K + scb * 8;

    auto stage = [&](int k0, int buf) {
      __bf16* Ad = sm + buf * 8192;
      __bf16* Bd = sm + 16384 + buf * 8192;
      GLOAD_LDS(gA + k0, Ad + t * 8);
      GLOAD_LDS(gA + (size_t)64 * lda + k0, Ad + (512 + t) * 8);
      GLOAD_LDS(gB + k0, Bd + t * 8);
      GLOAD_LDS(gB + (size_t)64 * K + k0, Bd + (512 + t) * 8);
    };

    int aoff[2][2], boff[4][2];
#pragma unroll
    for (int ks = 0; ks < 2; ++ks) {
#pragma unroll
      for (int i = 0; i < 2; ++i) {
        int ra = wr*32 + i*16 + lr;
        aoff[i][ks] = ra*64 + (((ks*4 + lg) ^ (ra & 7)) * 8);
      }
#pragma unroll
      for (int j = 0; j < 4; ++j) {
        int rb = wc*64 + j*16 + lr;
        boff[j][ks] = rb*64 + (((ks*4 + lg) ^ (rb & 7)) * 8);
      }
    }

    int NK = K >> 6;
    stage(0, 0);
    __syncthreads();
    for (int kt = 0; kt < NK; ++kt) {
      int cur = kt & 1;
      if (kt + 1 < NK) stage((kt + 1) << 6, cur ^ 1);  // prefetch flies under MFMA
      const __bf16* As = sm + cur * 8192;
      const __bf16* Bs = sm + 16384 + cur * 8192;
#pragma unroll
      for (int ks = 0; ks < 2; ++ks) {
        bf16x8 af[2], bfr[4];
#pragma unroll
        for (int i = 0; i < 2; ++i) af[i]  = *(const bf16x8*)(As + aoff[i][ks]);
#pragma unroll
        for (int j = 0; j < 4; ++j) bfr[j] = *(const bf16x8*)(Bs + boff[j][ks]);
        __builtin_amdgcn_s_setprio(1);
#pragma unroll
        for (int i = 0; i < 2; ++i)
#pragma unroll
          for (int j = 0; j < 4; ++j)
            acc[i][j] = mfma_bf16(af[i], bfr[j], acc[i][j]);
        __builtin_amdgcn_s_setprio(0);
      }
      __syncthreads();
    }

    if (EPI == 1) {
      int lbase = m0 & 511;
      float s1[4] = {0.f,0.f,0.f,0.f}, s2[4] = {0.f,0.f,0.f,0.f};
#pragma unroll
      for (int i = 0; i < 2; ++i)
#pragma unroll
        for (int j = 0; j < 4; ++j)
#pragma unroll
          for (int q = 0; q < 4; ++q) {
            int rrow = wr*32 + i*16 + lg*4 + q;
            int col = n0 + wc*64 + j*16 + lr;
            float v = acc[i][j][q] + bias[col];
            outQK[(size_t)(m0 + rrow) * N + col] = __float2bfloat16(v);
            if (lbase + rrow < lenb) { s1[j] += v; s2[j] += v*v; }
          }
#pragma unroll
      for (int j = 0; j < 4; ++j) {
        s1[j] += __shfl_xor(s1[j], 16); s1[j] += __shfl_xor(s1[j], 32);
        s2[j] += __shfl_xor(s2[j], 16); s2[j] += __shfl_xor(s2[j], 32);
      }
      float* fb = (float*)sm;   // [4 wr][128 cloc] x {s1,s2}
      if (lg == 0) {
#pragma unroll
        for (int j = 0; j < 4; ++j) {
          int cloc = wc*64 + j*16 + lr;
          fb[wr*128 + cloc] = s1[j];
          fb[512 + wr*128 + cloc] = s2[j];
        }
      }
      __syncthreads();
      if (t < 128) {
        pS [by*256 + bx*128 + t] = fb[t] + fb[128 + t] + fb[256 + t] + fb[384 + t];
        pS2[by*256 + bx*128 + t] = fb[512 + t] + fb[640 + t] + fb[768 + t] + fb[896 + t];
      }
    } else if (n0 < 1024) {
#pragma unroll
      for (int i = 0; i < 2; ++i)
#pragma unroll
        for (int j = 0; j < 4; ++j)
#pragma unroll
          for (int q = 0; q < 4; ++q) {
            int row = m0 + wr*32 + i*16 + lg*4 + q;
            int col = n0 + wc*64 + j*16 + lr;
            outQK[(size_t)row * 1024 + col] = __float2bfloat16(acc[i][j][q]);
          }
    } else {
      // V region: transpose via LDS (Ct[128][136]), coalesced 16-B stores
      __bf16* Ct = sm;
#pragma unroll
      for (int i = 0; i < 2; ++i)
#pragma unroll
        for (int j = 0; j < 4; ++j) {
          int col = wc*64 + j*16 + lr;
          int row0 = wr*32 + i*16 + lg*4;
          bf16x4 pv;
#pragma unroll
          for (int q = 0; q < 4; ++q) pv[q] = (__bf16)acc[i][j][q];
          *(bf16x4*)(Ct + col*136 + row0) = pv;
        }
      __syncthreads();
      int b = m0 >> 9, l0 = m0 & 511, gcol0 = n0 - 1024;
#pragma unroll
      for (int it = 0; it < 4; ++it) {
        int gg = it * 512 + t;
        int vv = gg >> 4, rc = gg & 15;
        bf16x8 val = *(const bf16x8*)(Ct + vv*136 + rc*8);
        int gc = gcol0 + vv, h = gc >> 6, vg = gc & 63;
        *(bf16x8*)((__bf16*)outVT + ((size_t)((b*HH + h)*64 + vg))*512 + l0 + rc*8) = val;
      }
    }
  } else if (EPI == 1 && t < 128) {
    pS [by*256 + bx*128 + t] = 0.f;
    pS2[by*256 + bx*128 + t] = 0.f;
  }

  if (EPI == 1) {
    // last-block BN finalize (device-scope; counter zeroed by prep_all each call)
    __syncthreads();
    __threadfence();
    if (t == 0) islast = (atomicAdd(cnt, 1) == (int)gridDim.x - 1);
    __syncthreads();
    if (islast) {
      __threadfence();
      int col = t & 255, part = t >> 8;       // 2 parts x 128 rows
      float s = 0.f, s2 = 0.f;
      for (int i = part*128; i < part*128 + 128; ++i) {
        s += pS[i*256 + col]; s2 += pS2[i*256 + col];
      }
      float* red = (float*)sm;
      __syncthreads();
      red[part*256 + col] = s;
      red[512 + part*256 + col] = s2;
      __syncthreads();
      if (t < 256) {
        float cv = 0.f;
        for (int i = 0; i < 64; ++i) cv += (float)lengths[i];
        float fs = red[t] + red[256 + t];
        float fs2 = red[512 + t] + red[768 + t];
        float mean = fs / cv;
        float var = fs2 / cv - mean * mean;
        float a = g[t] * rsqrtf(var + 1e-5f);
        aff[t] = a;
        aff[256 + t] = be[t] - mean * a;
      }
    }
  }
}

// ---------------- attention v9: LPT order, 3-buf counted vmcnt (unchanged) ----------------
__global__ __launch_bounds__(512)
void attn(__hip_bfloat16* QK, const __hip_bfloat16* __restrict__ VT,
          const int* __restrict__ lengths, const int* __restrict__ order) {
  int hw = blockIdx.x;                       // 2048 blocks
  int h = hw & 7, r = hw >> 3;
  int rank = r >> 2, qt = r & 3;
  int b = order[rank];
  int len = lengths[b];
  if (qt * 128 >= len) return;
  __shared__ __align__(16) __hip_bfloat16 Ks[3][2048];   // 32 keys x 64 d
  __shared__ __align__(16) __hip_bfloat16 Vs[3][2048];   // 64 v x 32 l
  __shared__ __align__(16) __hip_bfloat16 P[8][16][40];  // 32 keys + pad
  int t = threadIdx.x, wave = t >> 6, lane = t & 63, lr = lane & 15, lg = lane >> 4;
  int q0 = qt * 128 + wave * 16;
  const __hip_bfloat16* Qb = QK + (size_t)b*512*1024 + h*64;
  const __hip_bfloat16* Kb = QK + (size_t)b*512*1024 + 512 + h*64;
  const __hip_bfloat16* Vb = VT + (size_t)(b*HH + h)*64*512;

  bf16x8 qf0 = *(const bf16x8*)(Qb + (size_t)(q0 + lr)*1024 + lg*8);
  bf16x8 qf1 = *(const bf16x8*)(Qb + (size_t)(q0 + lr)*1024 + 32 + lg*8);
#pragma unroll
  for (int i = 0; i < 8; ++i) {
    qf0[i] = (__bf16)((float)qf0[i] * 0.18033688f);
    qf1[i] = (__bf16)((float)qf1[i] * 0.18033688f);
  }
  bf16x8 onesf;
#pragma unroll
  for (int i = 0; i < 8; ++i) onesf[i] = (__bf16)1.0f;

  int koff0[2], koff1[2];
#pragma unroll
  for (int kb = 0; kb < 2; ++kb) {
    int row = kb*16 + lr, sw = row & 7;
    koff0[kb] = row*64 + ((lg ^ sw) * 8);
    koff1[kb] = row*64 + (((lg + 4) ^ sw) * 8);
  }
  int voff[4];
#pragma unroll
  for (int vb = 0; vb < 4; ++vb) {
    int row = vb*16 + lr;
    voff[vb] = row*32 + ((lg ^ ((row >> 1) & 3)) * 8);
  }
  int ku = t & 255;
  int krow = ku >> 3, kcb = (ku & 7) ^ (krow & 7);
  const __hip_bfloat16* kgp = Kb + (size_t)krow*1024 + kcb*8;
  int vrow = ku >> 2, vcb = (ku & 3) ^ ((vrow >> 1) & 3);
  const __hip_bfloat16* vgp = Vb + (size_t)vrow*512 + vcb*8;

  int nt = (len + 31) >> 5;

  auto stage = [&](int kt, int buf) {
    if (t < 256) GLOAD_LDS(kgp + (size_t)kt*32768, &Ks[buf][ku*8]);
    else         GLOAD_LDS(vgp + kt*32,           &Vs[buf][ku*8]);
  };

  floatx4 O[4];
  floatx4 Ol = {0.f, 0.f, 0.f, 0.f};
#pragma unroll
  for (int vb = 0; vb < 4; ++vb)
#pragma unroll
    for (int i = 0; i < 4; ++i) O[vb][i] = 0.f;

  stage(0, 0);
  if (nt > 1) {
    stage(1, 1);
    asm volatile("s_waitcnt vmcnt(1)" ::: "memory");
  } else {
    asm volatile("s_waitcnt vmcnt(0)" ::: "memory");
  }
  __builtin_amdgcn_sched_barrier(0);
  __builtin_amdgcn_s_barrier();
  __builtin_amdgcn_sched_barrier(0);

  for (int kt = 0; kt < nt; ++kt) {
    int cur = kt % 3;
    if (kt + 2 < nt) stage(kt + 2, (kt + 2) % 3);
    int kb0 = kt * 32;
    const __hip_bfloat16* Kc = Ks[cur];
    const __hip_bfloat16* Vc = Vs[cur];

    floatx4 S[2];
    __builtin_amdgcn_s_setprio(1);
#pragma unroll
    for (int kb = 0; kb < 2; ++kb) {
      bf16x8 kf0 = *(const bf16x8*)(Kc + koff0[kb]);
      bf16x8 kf1 = *(const bf16x8*)(Kc + koff1[kb]);
      floatx4 s = {0.f, 0.f, 0.f, 0.f};
      s = mfma_bf16(kf0, qf0, s);
      s = mfma_bf16(kf1, qf1, s);
      S[kb] = s;
    }
    __builtin_amdgcn_s_setprio(0);
#pragma unroll
    for (int kb = 0; kb < 2; ++kb)
#pragma unroll
      for (int i = 0; i < 4; ++i) S[kb][i] = __builtin_amdgcn_exp2f(S[kb][i]);
    if (kb0 + 32 > len) {
#pragma unroll
      for (int kb = 0; kb < 2; ++kb)
#pragma unroll
        for (int i = 0; i < 4; ++i)
          if (kb0 + kb*16 + lg*4 + i >= len) S[kb][i] = 0.f;
    }
#pragma unroll
    for (int kb = 0; kb < 2; ++kb) {
      bf16x4 pv;
#pragma unroll
      for (int i = 0; i < 4; ++i) pv[i] = (__bf16)S[kb][i];
      *(bf16x4*)(&P[wave][lr][kb*16 + lg*4]) = pv;
    }
    bf16x8 pf = *(const bf16x8*)(&P[wave][lr][lg*8]);
    __builtin_amdgcn_s_setprio(1);
#pragma unroll
    for (int vb = 0; vb < 4; ++vb) {
      bf16x8 vf = *(const bf16x8*)(Vc + voff[vb]);
      O[vb] = mfma_bf16(pf, vf, O[vb]);
    }
    Ol = mfma_bf16(pf, onesf, Ol);
    __builtin_amdgcn_s_setprio(0);

    if (kt + 1 < nt) {
      if (kt + 2 < nt) asm volatile("s_waitcnt vmcnt(1)" ::: "memory");
      else             asm volatile("s_waitcnt vmcnt(0)" ::: "memory");
      __builtin_amdgcn_sched_barrier(0);
      __builtin_amdgcn_s_barrier();
      __builtin_amdgcn_sched_barrier(0);
    }
  }

#pragma unroll
  for (int vb = 0; vb < 4; ++vb)
#pragma unroll
    for (int i = 0; i < 4; ++i) {
      int q = q0 + lg*4 + i;
      float z = O[vb][i] / Ol[i];
      QK[(size_t)(b*512 + q)*1024 + h*64 + vb*16 + lr] = __float2bfloat16(z);
    }
}

// ---------------- BN-apply + ReLU + mask (bf16 in, row-skip) ----------------
__global__ __launch_bounds__(256)
void apply1(const __hip_bfloat16* __restrict__ Zr, const int* __restrict__ lengths,
            const float* __restrict__ aff, __hip_bfloat16* __restrict__ Zn) {
  int idx = blockIdx.x * 256 + threadIdx.x;
  int row = idx >> 6, c4 = (idx & 63) * 4;
  int b = row >> 9, l = row & 511;
  int lenb = lengths[b];
  if (l >= ((lenb + 127) & ~127)) return;    // rows never read by gemmZ2
  bool ok = l < lenb;
  bf16x4 z = *(const bf16x4*)((const __bf16*)Zr + (size_t)row*256 + c4);
  float4 a = *(const float4*)(aff + c4);
  float4 c = *(const float4*)(aff + 256 + c4);
  bf16x4 o;
  o[0] = (__bf16)(ok ? fmaxf(a.x*(float)z[0] + c.x, 0.f) : 0.f);
  o[1] = (__bf16)(ok ? fmaxf(a.y*(float)z[1] + c.y, 0.f) : 0.f);
  o[2] = (__bf16)(ok ? fmaxf(a.z*(float)z[2] + c.z, 0.f) : 0.f);
  o[3] = (__bf16)(ok ? fmaxf(a.w*(float)z[3] + c.w, 0.f) : 0.f);
  *(bf16x4*)((__bf16*)Zn + (size_t)row*256 + c4) = o;
}

__global__ __launch_bounds__(256)
void apply2(const __hip_bfloat16* __restrict__ Zr, const float* __restrict__ emb,
            const int* __restrict__ lengths, const float* __restrict__ aff,
            float* __restrict__ out) {
  int idx = blockIdx.x * 256 + threadIdx.x;
  int row = idx >> 6, c4 = (idx & 63) * 4;
  int b = row >> 9, l = row & 511;
  size_t base = (size_t)row*256 + c4;
  if (l >= lengths[b]) {                     // masked row: zeros, no loads
    float4 z = {0.f, 0.f, 0.f, 0.f};
    *(float4*)(out + base) = z;
    return;
  }
  bf16x4 zv = *(const bf16x4*)((const __bf16*)Zr + base);
  float4 e = *(const float4*)(emb + base);
  float4 a = *(const float4*)(aff + c4);
  float4 c = *(const float4*)(aff + 256 + c4);
  float4 o;
  o.x = fmaxf(a.x*(float)zv[0] + c.x + e.x, 0.f);
  o.y = fmaxf(a.y*(float)zv[1] + c.y + e.y, 0.f);
  o.z = fmaxf(a.z*(float)zv[2] + c.z + e.z, 0.f);
  o.w = fmaxf(a.w*(float)zv[3] + c.w + e.w, 0.f);
  *(float4*)(out + base) = o;
}

// ---------------- launch ----------------
extern "C" void kernel_launch(void* const* d_in, const int* in_sizes, int n_in,
                              void* d_out, int out_size, void* d_ws, size_t ws_size,
                              hipStream_t stream) {
  const float* emb   = (const float*)d_in[0];
  const float* boxes = (const float*)d_in[1];
  const int*   dlen  = (const int*)d_in[2];
  const float* Wq    = (const float*)d_in[3];
  const float* Wk    = (const float*)d_in[4];
  const float* Wv    = (const float*)d_in[5];
  const float* W1    = (const float*)d_in[6];
  const float* b1    = (const float*)d_in[7];
  const float* W2    = (const float*)d_in[8];
  const float* b2    = (const float*)d_in[9];
  const float* g1    = (const float*)d_in[10];
  const float* be1   = (const float*)d_in[11];
  const float* g2    = (const float*)d_in[12];
  const float* be2   = (const float*)d_in[13];
  float* out = (float*)d_out;

  // ws layout (bytes)
  const size_t oWqkvT = 0;          // 1536*320*2  = 983040
  const size_t oW1T   = 983040;     // 256*512*2   = 262144
  const size_t oW2T   = 1245184;    // 256*256*2   = 131072
  const size_t oAff1  = 1376256;    // 2048
  const size_t oAff2  = 1378304;    // 2048
  const size_t oPS    = 1380352;    // 256*256*4 = 262144
  const size_t oPS2   = 1642496;    // 262144
  const size_t oXbf   = 1904640;    // 32768*320*2 = 20971520 (reused by Z1n)
  const size_t oQK    = 22876160;   // 32768*1024*2= 67108864 (Z in-place; reused by Z2b)
  const size_t oVT    = 89985024;   // 8*64*64*512*2 = 33554432 (reused by Z1b)
  const size_t oOrd   = 123539456;  // 256
  const size_t oCnt   = 123539712;  // 8 (finalize counters)
  const size_t NEED   = 123539968;
  if (ws_size < NEED) { fprintf(stderr, "ws too small: %zu < %zu\n", ws_size, NEED); return; }

  char* w = (char*)d_ws;
  __hip_bfloat16* WqkvT = (__hip_bfloat16*)(w + oWqkvT);
  __hip_bfloat16* W1T   = (__hip_bfloat16*)(w + oW1T);
  __hip_bfloat16* W2T   = (__hip_bfloat16*)(w + oW2T);
  float* aff1 = (float*)(w + oAff1);
  float* aff2 = (float*)(w + oAff2);
  float* pS   = (float*)(w + oPS);
  float* pS2  = (float*)(w + oPS2);
  __hip_bfloat16* Xbf = (__hip_bfloat16*)(w + oXbf);
  __hip_bfloat16* Z1n = (__hip_bfloat16*)(w + oXbf);
  __hip_bfloat16* QK  = (__hip_bfloat16*)(w + oQK);
  __hip_bfloat16* Z2b = (__hip_bfloat16*)(w + oQK);
  __hip_bfloat16* VT  = (__hip_bfloat16*)(w + oVT);
  __hip_bfloat16* Z1b = (__hip_bfloat16*)(w + oVT);
  int* order = (int*)(w + oOrd);
  int* cnt   = (int*)(w + oCnt);

  prep_all<<<1 + 168 + ROWS/4 + ROWS/16, 256, 0, stream>>>(
      emb, boxes, Xbf, Wq, Wk, Wv, W1, W2, WqkvT, W1T, W2T, dlen, order, cnt);
  // QKV projection: [32768,320] x [320,1536], grid 12x256 XCD-chunked, LPT + M-sparse
  gemm_bt<0><<<12*256, 512, 0, stream>>>(
      Xbf, WqkvT, 12, NQKV, DD, DD, nullptr, QK, VT,
      dlen, order, nullptr, nullptr, nullptr, nullptr, nullptr, nullptr);
  attn<<<2048, 512, 0, stream>>>(QK, VT, dlen, order);
  // Z @ W1 + b1 (Z lives in QK cols 0..511, lda=1024), bf16 out + fused stats+finalize
  gemm_bt<1><<<2*256, 512, 0, stream>>>(
      QK, W1T, 2, 256, 512, 1024, b1, Z1b, nullptr,
      dlen, order, pS, pS2, g1, be1, aff1, cnt);
  apply1<<<ROWS/4, 256, 0, stream>>>(Z1b, dlen, aff1, Z1n);
  // Z1n @ W2 + b2, bf16 out + fused stats+finalize
  gemm_bt<1><<<2*256, 512, 0, stream>>>(
      Z1n, W2T, 2, 256, 256, 256, b2, Z2b, nullptr,
      dlen, order, pS, pS2, g2, be2, aff2, cnt + 1);
  apply2<<<ROWS/4, 256, 0, stream>>>(Z2b, emb, dlen, aff2, out);
}

// Round 16
// 156.059 us; speedup vs baseline: 2.7025x; 2.7025x over previous
//
#include <hip/hip_runtime.h>
#include <hip/hip_bf16.h>
#include <cstdio>

#define B_    64
#define L_    512
#define DIN   256
#define DPOS  64
#define DD    320
#define HH    8
#define ROWS  (B_*L_)     // 32768
#define NQKV  1536

typedef __attribute__((ext_vector_type(4))) float floatx4;
typedef __attribute__((ext_vector_type(8))) __bf16 bf16x8;
typedef __attribute__((ext_vector_type(4))) __bf16 bf16x4;

static __device__ __forceinline__ floatx4 mfma_bf16(bf16x8 a, bf16x8 b, floatx4 c) {
  return __builtin_amdgcn_mfma_f32_16x16x32_bf16(a, b, c, 0, 0, 0);
}

#define GLOAD_LDS(gp, lp) \
  __builtin_amdgcn_global_load_lds((const __attribute__((address_space(1))) void*)(gp), \
                                   (__attribute__((address_space(3))) void*)(lp), 16, 0, 0)

// ---------------- prep_all: sort | weight transpose | X convert (one launch) ----------------
// Grid = 1 + 168 + 10240. Block 0: argsort(lengths) desc.
// Blocks 1..168: one 64x64 W tile each. Blocks 169+: X = concat(emb,boxes) -> bf16.
__global__ __launch_bounds__(256)
void prep_all(const float* __restrict__ emb, const float* __restrict__ boxes,
              __hip_bfloat16* __restrict__ X,
              const float* __restrict__ Wq, const float* __restrict__ Wk,
              const float* __restrict__ Wv, const float* __restrict__ W1,
              const float* __restrict__ W2,
              __hip_bfloat16* __restrict__ WqkvT, __hip_bfloat16* __restrict__ W1T,
              __hip_bfloat16* __restrict__ W2T,
              const int* __restrict__ len, int* __restrict__ order) {
  __shared__ float tile[64][65];
  int blk = blockIdx.x, t = threadIdx.x;
  if (blk == 0) {
    if (t < 64) {
      int lb = len[t];
      int rank = 0;
      for (int j = 0; j < 64; ++j) {
        int lj = len[j];
        if (lj > lb || (lj == lb && j < t)) ++rank;
      }
      order[rank] = t;
    }
    return;
  }
  if (blk <= 168) {
    int wb = blk - 1;
    const float* src; __hip_bfloat16* dst; int n0, k0, ldsrc, lddst;
    if (wb < 120) {
      int m = wb / 40, rel = wb % 40;
      src = (m == 0) ? Wq : (m == 1) ? Wk : Wv;
      dst = WqkvT + (size_t)m * 512 * DD;
      n0 = (rel / 5) * 64; k0 = (rel % 5) * 64; ldsrc = 512; lddst = DD;
    } else if (wb < 152) {
      int rel = wb - 120;
      src = W1; dst = W1T; n0 = (rel >> 3) * 64; k0 = (rel & 7) * 64; ldsrc = 256; lddst = 512;
    } else {
      int rel = wb - 152;
      src = W2; dst = W2T; n0 = (rel >> 2) * 64; k0 = (rel & 3) * 64; ldsrc = 256; lddst = 256;
    }
#pragma unroll
    for (int i = 0; i < 16; ++i) {
      int e = i * 256 + t, kr = e >> 6, nc = e & 63;
      tile[kr][nc] = src[(size_t)(k0 + kr) * ldsrc + n0 + nc];
    }
    __syncthreads();
#pragma unroll
    for (int i = 0; i < 4; ++i) {
      int ww = i * 256 + t, nr = ww >> 4, kc = (ww & 15) * 4;
      bf16x4 o;
      o[0] = (__bf16)tile[kc][nr];   o[1] = (__bf16)tile[kc+1][nr];
      o[2] = (__bf16)tile[kc+2][nr]; o[3] = (__bf16)tile[kc+3][nr];
      *(bf16x4*)(dst + (size_t)(n0 + nr) * lddst + k0 + kc) = o;
    }
    return;
  }
  int bb = blk - 169;
  if (bb < ROWS/4) {
    int idx = bb * 256 + t;                      // ROWS*64 threads, 4 f32 each
    int row = idx >> 6, c4 = (idx & 63) * 4;
    const float4 v = *(const float4*)(emb + (size_t)idx * 4);
    bf16x4 o; o[0] = (__bf16)v.x; o[1] = (__bf16)v.y; o[2] = (__bf16)v.z; o[3] = (__bf16)v.w;
    *(bf16x4*)((__bf16*)X + (size_t)row * DD + c4) = o;
  } else {
    int idx = (bb - ROWS/4) * 256 + t;           // ROWS*16 threads
    int row = idx >> 4, c4 = (idx & 15) * 4;
    const float4 v = *(const float4*)(boxes + (size_t)idx * 4);
    bf16x4 o; o[0] = (__bf16)v.x; o[1] = (__bf16)v.y; o[2] = (__bf16)v.z; o[3] = (__bf16)v.w;
    *(bf16x4*)((__bf16*)X + (size_t)row * DD + DIN + c4) = o;
  }
}

// ---------------- GEMM v11 (R14): 128x128 tile, BK=64 dbuf, 512 threads, partials only ----------------
// LPT via order[] (XCD-striped). M-sparse skip. M = 32768 (256 by-blocks).
// EPI 0: QKV split (bf16): n0<1024 -> QK; else VT[b,h,v,l] via LDS transpose.
// EPI 1: bf16 out + bias; fused masked BN partials (f32 acc) -> pS/pS2.
template<int EPI>
__global__ __launch_bounds__(512)
void gemm_bt(const __hip_bfloat16* __restrict__ A, const __hip_bfloat16* __restrict__ BT,
             int nbx, int N, int K, int lda,
             const float* __restrict__ bias,
             __hip_bfloat16* __restrict__ outQK, __hip_bfloat16* __restrict__ outVT,
             const int* __restrict__ lengths, const int* __restrict__ order,
             float* __restrict__ pS, float* __restrict__ pS2) {
  __shared__ __align__(16) __bf16 sm[32768];  // 64 KB: A0 A1 | B0 B1 (8192 elems each)
  int hw = blockIdx.x;
  int lidx = (hw & 7) * ((int)gridDim.x >> 3) + (hw >> 3);
  int bx = lidx % nbx, by = lidx / nbx;       // by in [0,256)
  int t = threadIdx.x;
  int brank = ((by & 31) >> 2) * 8 + (by >> 5);
  int bb = order[brank];
  int m0 = bb * 512 + (by & 3) * 128;
  int n0 = bx * 128;
  int lenb = lengths[bb];
  if ((m0 & 511) >= lenb) {            // fully-masked 128-row block: skip
    if (EPI == 1 && t < 128) {
      pS [by*256 + bx*128 + t] = 0.f;
      pS2[by*256 + bx*128 + t] = 0.f;
    }
    return;
  }
  int wave = t >> 6, lane = t & 63, lr = lane & 15, lg = lane >> 4;
  int wr = wave >> 1, wc = wave & 1;   // wr: 32 rows each; wc: 64 cols each
  floatx4 acc[2][4];
#pragma unroll
  for (int i = 0; i < 2; ++i)
#pragma unroll
    for (int j = 0; j < 4; ++j)
#pragma unroll
      for (int q = 0; q < 4; ++q) acc[i][j][q] = 0.f;

  int srow = t >> 3;
  int scb = (t & 7) ^ (srow & 7);
  const __bf16* gA = (const __bf16*)A + (size_t)(m0 + srow) * lda + scb * 8;
  const __bf16* gB = (const __bf16*)BT + (size_t)(n0 + srow) * K + scb * 8;

  auto stage = [&](int k0, int buf) {
    __bf16* Ad = sm + buf * 8192;
    __bf16* Bd = sm + 16384 + buf * 8192;
    GLOAD_LDS(gA + k0, Ad + t * 8);
    GLOAD_LDS(gA + (size_t)64 * lda + k0, Ad + (512 + t) * 8);
    GLOAD_LDS(gB + k0, Bd + t * 8);
    GLOAD_LDS(gB + (size_t)64 * K + k0, Bd + (512 + t) * 8);
  };

  int aoff[2][2], boff[4][2];
#pragma unroll
  for (int ks = 0; ks < 2; ++ks) {
#pragma unroll
    for (int i = 0; i < 2; ++i) {
      int ra = wr*32 + i*16 + lr;
      aoff[i][ks] = ra*64 + (((ks*4 + lg) ^ (ra & 7)) * 8);
    }
#pragma unroll
    for (int j = 0; j < 4; ++j) {
      int rb = wc*64 + j*16 + lr;
      boff[j][ks] = rb*64 + (((ks*4 + lg) ^ (rb & 7)) * 8);
    }
  }

  int NK = K >> 6;
  stage(0, 0);
  __syncthreads();
  for (int kt = 0; kt < NK; ++kt) {
    int cur = kt & 1;
    if (kt + 1 < NK) stage((kt + 1) << 6, cur ^ 1);  // prefetch flies under MFMA
    const __bf16* As = sm + cur * 8192;
    const __bf16* Bs = sm + 16384 + cur * 8192;
#pragma unroll
    for (int ks = 0; ks < 2; ++ks) {
      bf16x8 af[2], bfr[4];
#pragma unroll
      for (int i = 0; i < 2; ++i) af[i]  = *(const bf16x8*)(As + aoff[i][ks]);
#pragma unroll
      for (int j = 0; j < 4; ++j) bfr[j] = *(const bf16x8*)(Bs + boff[j][ks]);
      __builtin_amdgcn_s_setprio(1);
#pragma unroll
      for (int i = 0; i < 2; ++i)
#pragma unroll
        for (int j = 0; j < 4; ++j)
          acc[i][j] = mfma_bf16(af[i], bfr[j], acc[i][j]);
      __builtin_amdgcn_s_setprio(0);
    }
    __syncthreads();
  }

  if (EPI == 1) {
    int lbase = m0 & 511;
    float s1[4] = {0.f,0.f,0.f,0.f}, s2[4] = {0.f,0.f,0.f,0.f};
#pragma unroll
    for (int i = 0; i < 2; ++i)
#pragma unroll
      for (int j = 0; j < 4; ++j)
#pragma unroll
        for (int q = 0; q < 4; ++q) {
          int rrow = wr*32 + i*16 + lg*4 + q;
          int col = n0 + wc*64 + j*16 + lr;
          float v = acc[i][j][q] + bias[col];
          outQK[(size_t)(m0 + rrow) * N + col] = __float2bfloat16(v);
          if (lbase + rrow < lenb) { s1[j] += v; s2[j] += v*v; }
        }
#pragma unroll
    for (int j = 0; j < 4; ++j) {
      s1[j] += __shfl_xor(s1[j], 16); s1[j] += __shfl_xor(s1[j], 32);
      s2[j] += __shfl_xor(s2[j], 16); s2[j] += __shfl_xor(s2[j], 32);
    }
    float* fb = (float*)sm;   // [4 wr][128 cloc] x {s1,s2} = 4KB
    if (lg == 0) {
#pragma unroll
      for (int j = 0; j < 4; ++j) {
        int cloc = wc*64 + j*16 + lr;
        fb[wr*128 + cloc] = s1[j];
        fb[512 + wr*128 + cloc] = s2[j];
      }
    }
    __syncthreads();
    if (t < 128) {
      pS [by*256 + bx*128 + t] = fb[t] + fb[128 + t] + fb[256 + t] + fb[384 + t];
      pS2[by*256 + bx*128 + t] = fb[512 + t] + fb[640 + t] + fb[768 + t] + fb[896 + t];
    }
  } else if (n0 < 1024) {
#pragma unroll
    for (int i = 0; i < 2; ++i)
#pragma unroll
      for (int j = 0; j < 4; ++j)
#pragma unroll
        for (int q = 0; q < 4; ++q) {
          int row = m0 + wr*32 + i*16 + lg*4 + q;
          int col = n0 + wc*64 + j*16 + lr;
          outQK[(size_t)row * 1024 + col] = __float2bfloat16(acc[i][j][q]);
        }
  } else {
    // V region: transpose via LDS (Ct[128][136] = 34816 B), coalesced 16-B stores
    __bf16* Ct = sm;
#pragma unroll
    for (int i = 0; i < 2; ++i)
#pragma unroll
      for (int j = 0; j < 4; ++j) {
        int col = wc*64 + j*16 + lr;
        int row0 = wr*32 + i*16 + lg*4;
        bf16x4 pv;
#pragma unroll
        for (int q = 0; q < 4; ++q) pv[q] = (__bf16)acc[i][j][q];
        *(bf16x4*)(Ct + col*136 + row0) = pv;
      }
    __syncthreads();
    int b = m0 >> 9, l0 = m0 & 511, gcol0 = n0 - 1024;
#pragma unroll
    for (int it = 0; it < 4; ++it) {
      int g = it * 512 + t;
      int vv = g >> 4, rc = g & 15;
      bf16x8 val = *(const bf16x8*)(Ct + vv*136 + rc*8);
      int gc = gcol0 + vv, h = gc >> 6, vg = gc & 63;
      *(bf16x8*)((__bf16*)outVT + ((size_t)((b*HH + h)*64 + vg))*512 + l0 + rc*8) = val;
    }
  }
}

// ---------------- attention v9: LPT order, 3-buf counted vmcnt (unchanged) ----------------
__global__ __launch_bounds__(512)
void attn(__hip_bfloat16* QK, const __hip_bfloat16* __restrict__ VT,
          const int* __restrict__ lengths, const int* __restrict__ order) {
  int hw = blockIdx.x;                       // 2048 blocks
  int h = hw & 7, r = hw >> 3;
  int rank = r >> 2, qt = r & 3;
  int b = order[rank];
  int len = lengths[b];
  if (qt * 128 >= len) return;
  __shared__ __align__(16) __hip_bfloat16 Ks[3][2048];   // 32 keys x 64 d
  __shared__ __align__(16) __hip_bfloat16 Vs[3][2048];   // 64 v x 32 l
  __shared__ __align__(16) __hip_bfloat16 P[8][16][40];  // 32 keys + pad
  int t = threadIdx.x, wave = t >> 6, lane = t & 63, lr = lane & 15, lg = lane >> 4;
  int q0 = qt * 128 + wave * 16;
  const __hip_bfloat16* Qb = QK + (size_t)b*512*1024 + h*64;
  const __hip_bfloat16* Kb = QK + (size_t)b*512*1024 + 512 + h*64;
  const __hip_bfloat16* Vb = VT + (size_t)(b*HH + h)*64*512;

  bf16x8 qf0 = *(const bf16x8*)(Qb + (size_t)(q0 + lr)*1024 + lg*8);
  bf16x8 qf1 = *(const bf16x8*)(Qb + (size_t)(q0 + lr)*1024 + 32 + lg*8);
#pragma unroll
  for (int i = 0; i < 8; ++i) {
    qf0[i] = (__bf16)((float)qf0[i] * 0.18033688f);
    qf1[i] = (__bf16)((float)qf1[i] * 0.18033688f);
  }
  bf16x8 onesf;
#pragma unroll
  for (int i = 0; i < 8; ++i) onesf[i] = (__bf16)1.0f;

  int koff0[2], koff1[2];
#pragma unroll
  for (int kb = 0; kb < 2; ++kb) {
    int row = kb*16 + lr, sw = row & 7;
    koff0[kb] = row*64 + ((lg ^ sw) * 8);
    koff1[kb] = row*64 + (((lg + 4) ^ sw) * 8);
  }
  int voff[4];
#pragma unroll
  for (int vb = 0; vb < 4; ++vb) {
    int row = vb*16 + lr;
    voff[vb] = row*32 + ((lg ^ ((row >> 1) & 3)) * 8);
  }
  int ku = t & 255;
  int krow = ku >> 3, kcb = (ku & 7) ^ (krow & 7);
  const __hip_bfloat16* kgp = Kb + (size_t)krow*1024 + kcb*8;
  int vrow = ku >> 2, vcb = (ku & 3) ^ ((vrow >> 1) & 3);
  const __hip_bfloat16* vgp = Vb + (size_t)vrow*512 + vcb*8;

  int nt = (len + 31) >> 5;

  auto stage = [&](int kt, int buf) {
    if (t < 256) GLOAD_LDS(kgp + (size_t)kt*32768, &Ks[buf][ku*8]);
    else         GLOAD_LDS(vgp + kt*32,           &Vs[buf][ku*8]);
  };

  floatx4 O[4];
  floatx4 Ol = {0.f, 0.f, 0.f, 0.f};
#pragma unroll
  for (int vb = 0; vb < 4; ++vb)
#pragma unroll
    for (int i = 0; i < 4; ++i) O[vb][i] = 0.f;

  stage(0, 0);
  if (nt > 1) {
    stage(1, 1);
    asm volatile("s_waitcnt vmcnt(1)" ::: "memory");
  } else {
    asm volatile("s_waitcnt vmcnt(0)" ::: "memory");
  }
  __builtin_amdgcn_sched_barrier(0);
  __builtin_amdgcn_s_barrier();
  __builtin_amdgcn_sched_barrier(0);

  for (int kt = 0; kt < nt; ++kt) {
    int cur = kt % 3;
    if (kt + 2 < nt) stage(kt + 2, (kt + 2) % 3);
    int kb0 = kt * 32;
    const __hip_bfloat16* Kc = Ks[cur];
    const __hip_bfloat16* Vc = Vs[cur];

    floatx4 S[2];
    __builtin_amdgcn_s_setprio(1);
#pragma unroll
    for (int kb = 0; kb < 2; ++kb) {
      bf16x8 kf0 = *(const bf16x8*)(Kc + koff0[kb]);
      bf16x8 kf1 = *(const bf16x8*)(Kc + koff1[kb]);
      floatx4 s = {0.f, 0.f, 0.f, 0.f};
      s = mfma_bf16(kf0, qf0, s);
      s = mfma_bf16(kf1, qf1, s);
      S[kb] = s;
    }
    __builtin_amdgcn_s_setprio(0);
#pragma unroll
    for (int kb = 0; kb < 2; ++kb)
#pragma unroll
      for (int i = 0; i < 4; ++i) S[kb][i] = __builtin_amdgcn_exp2f(S[kb][i]);
    if (kb0 + 32 > len) {
#pragma unroll
      for (int kb = 0; kb < 2; ++kb)
#pragma unroll
        for (int i = 0; i < 4; ++i)
          if (kb0 + kb*16 + lg*4 + i >= len) S[kb][i] = 0.f;
    }
#pragma unroll
    for (int kb = 0; kb < 2; ++kb) {
      bf16x4 pv;
#pragma unroll
      for (int i = 0; i < 4; ++i) pv[i] = (__bf16)S[kb][i];
      *(bf16x4*)(&P[wave][lr][kb*16 + lg*4]) = pv;
    }
    bf16x8 pf = *(const bf16x8*)(&P[wave][lr][lg*8]);
    __builtin_amdgcn_s_setprio(1);
#pragma unroll
    for (int vb = 0; vb < 4; ++vb) {
      bf16x8 vf = *(const bf16x8*)(Vc + voff[vb]);
      O[vb] = mfma_bf16(pf, vf, O[vb]);
    }
    Ol = mfma_bf16(pf, onesf, Ol);
    __builtin_amdgcn_s_setprio(0);

    if (kt + 1 < nt) {
      if (kt + 2 < nt) asm volatile("s_waitcnt vmcnt(1)" ::: "memory");
      else             asm volatile("s_waitcnt vmcnt(0)" ::: "memory");
      __builtin_amdgcn_sched_barrier(0);
      __builtin_amdgcn_s_barrier();
      __builtin_amdgcn_sched_barrier(0);
    }
  }

#pragma unroll
  for (int vb = 0; vb < 4; ++vb)
#pragma unroll
    for (int i = 0; i < 4; ++i) {
      int q = q0 + lg*4 + i;
      float z = O[vb][i] / Ol[i];
      QK[(size_t)(b*512 + q)*1024 + h*64 + vb*16 + lr] = __float2bfloat16(z);
    }
}

// ---------------- BN finalize: 1024-thread parallel partial sum ----------------
__global__ __launch_bounds__(1024)
void stats_fin(const float* __restrict__ pS, const float* __restrict__ pS2,
               const int* __restrict__ lengths, const float* __restrict__ g,
               const float* __restrict__ be, float* __restrict__ aff) {
  __shared__ float red[2048];
  int t = threadIdx.x, col = t & 255, part = t >> 8;
  float s = 0.f, s2 = 0.f;
  for (int i = part*64; i < part*64 + 64; ++i) {
    s += pS[i*256 + col]; s2 += pS2[i*256 + col];
  }
  red[part*256 + col] = s;
  red[1024 + part*256 + col] = s2;
  __syncthreads();
  if (t < 256) {
    float cnt = 0.f;
    for (int i = 0; i < 64; ++i) cnt += (float)lengths[i];
    float fs = red[t] + red[256 + t] + red[512 + t] + red[768 + t];
    float fs2 = red[1024 + t] + red[1280 + t] + red[1536 + t] + red[1792 + t];
    float mean = fs / cnt;
    float var = fs2 / cnt - mean * mean;
    float a = g[t] * rsqrtf(var + 1e-5f);
    aff[t] = a;
    aff[256 + t] = be[t] - mean * a;
  }
}

// ---------------- BN-apply + ReLU + mask (bf16 in, row-skip) ----------------
__global__ __launch_bounds__(256)
void apply1(const __hip_bfloat16* __restrict__ Zr, const int* __restrict__ lengths,
            const float* __restrict__ aff, __hip_bfloat16* __restrict__ Zn) {
  int idx = blockIdx.x * 256 + threadIdx.x;
  int row = idx >> 6, c4 = (idx & 63) * 4;
  int b = row >> 9, l = row & 511;
  int lenb = lengths[b];
  if (l >= ((lenb + 127) & ~127)) return;    // rows never read by gemmZ2
  bool ok = l < lenb;
  bf16x4 z = *(const bf16x4*)((const __bf16*)Zr + (size_t)row*256 + c4);
  float4 a = *(const float4*)(aff + c4);
  float4 c = *(const float4*)(aff + 256 + c4);
  bf16x4 o;
  o[0] = (__bf16)(ok ? fmaxf(a.x*(float)z[0] + c.x, 0.f) : 0.f);
  o[1] = (__bf16)(ok ? fmaxf(a.y*(float)z[1] + c.y, 0.f) : 0.f);
  o[2] = (__bf16)(ok ? fmaxf(a.z*(float)z[2] + c.z, 0.f) : 0.f);
  o[3] = (__bf16)(ok ? fmaxf(a.w*(float)z[3] + c.w, 0.f) : 0.f);
  *(bf16x4*)((__bf16*)Zn + (size_t)row*256 + c4) = o;
}

__global__ __launch_bounds__(256)
void apply2(const __hip_bfloat16* __restrict__ Zr, const float* __restrict__ emb,
            const int* __restrict__ lengths, const float* __restrict__ aff,
            float* __restrict__ out) {
  int idx = blockIdx.x * 256 + threadIdx.x;
  int row = idx >> 6, c4 = (idx & 63) * 4;
  int b = row >> 9, l = row & 511;
  size_t base = (size_t)row*256 + c4;
  if (l >= lengths[b]) {                     // masked row: zeros, no loads
    float4 z = {0.f, 0.f, 0.f, 0.f};
    *(float4*)(out + base) = z;
    return;
  }
  bf16x4 zv = *(const bf16x4*)((const __bf16*)Zr + base);
  float4 e = *(const float4*)(emb + base);
  float4 a = *(const float4*)(aff + c4);
  float4 c = *(const float4*)(aff + 256 + c4);
  float4 o;
  o.x = fmaxf(a.x*(float)zv[0] + c.x + e.x, 0.f);
  o.y = fmaxf(a.y*(float)zv[1] + c.y + e.y, 0.f);
  o.z = fmaxf(a.z*(float)zv[2] + c.z + e.z, 0.f);
  o.w = fmaxf(a.w*(float)zv[3] + c.w + e.w, 0.f);
  *(float4*)(out + base) = o;
}

// ---------------- launch ----------------
extern "C" void kernel_launch(void* const* d_in, const int* in_sizes, int n_in,
                              void* d_out, int out_size, void* d_ws, size_t ws_size,
                              hipStream_t stream) {
  const float* emb   = (const float*)d_in[0];
  const float* boxes = (const float*)d_in[1];
  const int*   dlen  = (const int*)d_in[2];
  const float* Wq    = (const float*)d_in[3];
  const float* Wk    = (const float*)d_in[4];
  const float* Wv    = (const float*)d_in[5];
  const float* W1    = (const float*)d_in[6];
  const float* b1    = (const float*)d_in[7];
  const float* W2    = (const float*)d_in[8];
  const float* b2    = (const float*)d_in[9];
  const float* g1    = (const float*)d_in[10];
  const float* be1   = (const float*)d_in[11];
  const float* g2    = (const float*)d_in[12];
  const float* be2   = (const float*)d_in[13];
  float* out = (float*)d_out;

  // ws layout (bytes)
  const size_t oWqkvT = 0;          // 1536*320*2  = 983040
  const size_t oW1T   = 983040;     // 256*512*2   = 262144
  const size_t oW2T   = 1245184;    // 256*256*2   = 131072
  const size_t oAff1  = 1376256;    // 2048
  const size_t oAff2  = 1378304;    // 2048
  const size_t oPS    = 1380352;    // 256*256*4 = 262144
  const size_t oPS2   = 1642496;    // 262144
  const size_t oXbf   = 1904640;    // 32768*320*2 = 20971520 (reused by Z1n)
  const size_t oQK    = 22876160;   // 32768*1024*2= 67108864 (Z in-place; reused by Z2b)
  const size_t oVT    = 89985024;   // 8*64*64*512*2 = 33554432 (reused by Z1b)
  const size_t oOrd   = 123539456;  // 256
  const size_t NEED   = 123539712;
  if (ws_size < NEED) { fprintf(stderr, "ws too small: %zu < %zu\n", ws_size, NEED); return; }

  char* w = (char*)d_ws;
  __hip_bfloat16* WqkvT = (__hip_bfloat16*)(w + oWqkvT);
  __hip_bfloat16* W1T   = (__hip_bfloat16*)(w + oW1T);
  __hip_bfloat16* W2T   = (__hip_bfloat16*)(w + oW2T);
  float* aff1 = (float*)(w + oAff1);
  float* aff2 = (float*)(w + oAff2);
  float* pS   = (float*)(w + oPS);
  float* pS2  = (float*)(w + oPS2);
  __hip_bfloat16* Xbf = (__hip_bfloat16*)(w + oXbf);
  __hip_bfloat16* Z1n = (__hip_bfloat16*)(w + oXbf);
  __hip_bfloat16* QK  = (__hip_bfloat16*)(w + oQK);
  __hip_bfloat16* Z2b = (__hip_bfloat16*)(w + oQK);
  __hip_bfloat16* VT  = (__hip_bfloat16*)(w + oVT);
  __hip_bfloat16* Z1b = (__hip_bfloat16*)(w + oVT);
  int* order = (int*)(w + oOrd);

  prep_all<<<1 + 168 + ROWS/4 + ROWS/16, 256, 0, stream>>>(
      emb, boxes, Xbf, Wq, Wk, Wv, W1, W2, WqkvT, W1T, W2T, dlen, order);
  // QKV projection: [32768,320] x [320,1536], grid 12x256 XCD-chunked, LPT + M-sparse
  gemm_bt<0><<<12*256, 512, 0, stream>>>(
      Xbf, WqkvT, 12, NQKV, DD, DD, nullptr, QK, VT,
      dlen, order, nullptr, nullptr);
  attn<<<2048, 512, 0, stream>>>(QK, VT, dlen, order);
  // Z @ W1 + b1 (Z lives in QK cols 0..511, lda=1024), bf16 out + fused stats
  gemm_bt<1><<<2*256, 512, 0, stream>>>(
      QK, W1T, 2, 256, 512, 1024, b1, Z1b, nullptr,
      dlen, order, pS, pS2);
  stats_fin<<<1, 1024, 0, stream>>>(pS, pS2, dlen, g1, be1, aff1);
  apply1<<<ROWS/4, 256, 0, stream>>>(Z1b, dlen, aff1, Z1n);
  // Z1n @ W2 + b2, bf16 out + fused stats
  gemm_bt<1><<<2*256, 512, 0, stream>>>(
      Z1n, W2T, 2, 256, 256, 256, b2, Z2b, nullptr,
      dlen, order, pS, pS2);
  stats_fin<<<1, 1024, 0, stream>>>(pS, pS2, dlen, g2, be2, aff2);
  apply2<<<ROWS/4, 256, 0, stream>>>(Z2b, emb, dlen, aff2, out);
}

// Round 18
// 154.325 us; speedup vs baseline: 2.7328x; 1.0112x over previous
//
#include <hip/hip_runtime.h>
#include <hip/hip_bf16.h>
#include <cstdio>

#define B_    64
#define L_    512
#define DIN   256
#define DPOS  64
#define DD    320
#define HH    8
#define ROWS  (B_*L_)     // 32768
#define NQKV  1536

typedef __attribute__((ext_vector_type(4))) float floatx4;
typedef __attribute__((ext_vector_type(8))) __bf16 bf16x8;
typedef __attribute__((ext_vector_type(4))) __bf16 bf16x4;

static __device__ __forceinline__ floatx4 mfma_bf16(bf16x8 a, bf16x8 b, floatx4 c) {
  return __builtin_amdgcn_mfma_f32_16x16x32_bf16(a, b, c, 0, 0, 0);
}

#define GLOAD_LDS(gp, lp) \
  __builtin_amdgcn_global_load_lds((const __attribute__((address_space(1))) void*)(gp), \
                                   (__attribute__((address_space(3))) void*)(lp), 16, 0, 0)

// ---------------- prep_all: sort | weight transpose | X convert (one launch) ----------------
__global__ __launch_bounds__(256)
void prep_all(const float* __restrict__ emb, const float* __restrict__ boxes,
              __hip_bfloat16* __restrict__ X,
              const float* __restrict__ Wq, const float* __restrict__ Wk,
              const float* __restrict__ Wv, const float* __restrict__ W1,
              const float* __restrict__ W2,
              __hip_bfloat16* __restrict__ WqkvT, __hip_bfloat16* __restrict__ W1T,
              __hip_bfloat16* __restrict__ W2T,
              const int* __restrict__ len, int* __restrict__ order) {
  __shared__ float tile[64][65];
  int blk = blockIdx.x, t = threadIdx.x;
  if (blk == 0) {
    if (t < 64) {
      int lb = len[t];
      int rank = 0;
      for (int j = 0; j < 64; ++j) {
        int lj = len[j];
        if (lj > lb || (lj == lb && j < t)) ++rank;
      }
      order[rank] = t;
    }
    return;
  }
  if (blk <= 168) {
    int wb = blk - 1;
    const float* src; __hip_bfloat16* dst; int n0, k0, ldsrc, lddst;
    if (wb < 120) {
      int m = wb / 40, rel = wb % 40;
      src = (m == 0) ? Wq : (m == 1) ? Wk : Wv;
      dst = WqkvT + (size_t)m * 512 * DD;
      n0 = (rel / 5) * 64; k0 = (rel % 5) * 64; ldsrc = 512; lddst = DD;
    } else if (wb < 152) {
      int rel = wb - 120;
      src = W1; dst = W1T; n0 = (rel >> 3) * 64; k0 = (rel & 7) * 64; ldsrc = 256; lddst = 512;
    } else {
      int rel = wb - 152;
      src = W2; dst = W2T; n0 = (rel >> 2) * 64; k0 = (rel & 3) * 64; ldsrc = 256; lddst = 256;
    }
#pragma unroll
    for (int i = 0; i < 16; ++i) {
      int e = i * 256 + t, kr = e >> 6, nc = e & 63;
      tile[kr][nc] = src[(size_t)(k0 + kr) * ldsrc + n0 + nc];
    }
    __syncthreads();
#pragma unroll
    for (int i = 0; i < 4; ++i) {
      int ww = i * 256 + t, nr = ww >> 4, kc = (ww & 15) * 4;
      bf16x4 o;
      o[0] = (__bf16)tile[kc][nr];   o[1] = (__bf16)tile[kc+1][nr];
      o[2] = (__bf16)tile[kc+2][nr]; o[3] = (__bf16)tile[kc+3][nr];
      *(bf16x4*)(dst + (size_t)(n0 + nr) * lddst + k0 + kc) = o;
    }
    return;
  }
  int bb = blk - 169;
  if (bb < ROWS/4) {
    int idx = bb * 256 + t;                      // ROWS*64 threads, 4 f32 each
    int row = idx >> 6, c4 = (idx & 63) * 4;
    const float4 v = *(const float4*)(emb + (size_t)idx * 4);
    bf16x4 o; o[0] = (__bf16)v.x; o[1] = (__bf16)v.y; o[2] = (__bf16)v.z; o[3] = (__bf16)v.w;
    *(bf16x4*)((__bf16*)X + (size_t)row * DD + c4) = o;
  } else {
    int idx = (bb - ROWS/4) * 256 + t;           // ROWS*16 threads
    int row = idx >> 4, c4 = (idx & 15) * 4;
    const float4 v = *(const float4*)(boxes + (size_t)idx * 4);
    bf16x4 o; o[0] = (__bf16)v.x; o[1] = (__bf16)v.y; o[2] = (__bf16)v.z; o[3] = (__bf16)v.w;
    *(bf16x4*)((__bf16*)X + (size_t)row * DD + DIN + c4) = o;
  }
}

// ---------------- GEMM v11: 128x128 tile, BK=64 dbuf, 512 threads (R16 known-good) ----------------
// LPT via order[] (XCD-striped). M-sparse skip. M = 32768 (256 by-blocks).
// EPI 0: QKV split (bf16): n0<1024 -> QK; else VT[b,h,v,l] via LDS transpose.
// EPI 1: bf16 out + bias; fused masked BN partials (f32 acc) -> pS/pS2.
template<int EPI>
__global__ __launch_bounds__(512)
void gemm_bt(const __hip_bfloat16* __restrict__ A, const __hip_bfloat16* __restrict__ BT,
             int nbx, int N, int K, int lda,
             const float* __restrict__ bias,
             __hip_bfloat16* __restrict__ outQK, __hip_bfloat16* __restrict__ outVT,
             const int* __restrict__ lengths, const int* __restrict__ order,
             float* __restrict__ pS, float* __restrict__ pS2) {
  __shared__ __align__(16) __bf16 sm[32768];  // 64 KB: A0 A1 | B0 B1 (8192 elems each)
  int hw = blockIdx.x;
  int lidx = (hw & 7) * ((int)gridDim.x >> 3) + (hw >> 3);
  int bx = lidx % nbx, by = lidx / nbx;       // by in [0,256)
  int t = threadIdx.x;
  int brank = ((by & 31) >> 2) * 8 + (by >> 5);
  int bb = order[brank];
  int m0 = bb * 512 + (by & 3) * 128;
  int n0 = bx * 128;
  int lenb = lengths[bb];
  if ((m0 & 511) >= lenb) {            // fully-masked 128-row block: skip
    if (EPI == 1 && t < 128) {
      pS [by*256 + bx*128 + t] = 0.f;
      pS2[by*256 + bx*128 + t] = 0.f;
    }
    return;
  }
  int wave = t >> 6, lane = t & 63, lr = lane & 15, lg = lane >> 4;
  int wr = wave >> 1, wc = wave & 1;   // wr: 32 rows each; wc: 64 cols each
  floatx4 acc[2][4];
#pragma unroll
  for (int i = 0; i < 2; ++i)
#pragma unroll
    for (int j = 0; j < 4; ++j)
#pragma unroll
      for (int q = 0; q < 4; ++q) acc[i][j][q] = 0.f;

  int srow = t >> 3;
  int scb = (t & 7) ^ (srow & 7);
  const __bf16* gA = (const __bf16*)A + (size_t)(m0 + srow) * lda + scb * 8;
  const __bf16* gB = (const __bf16*)BT + (size_t)(n0 + srow) * K + scb * 8;

  auto stage = [&](int k0, int buf) {
    __bf16* Ad = sm + buf * 8192;
    __bf16* Bd = sm + 16384 + buf * 8192;
    GLOAD_LDS(gA + k0, Ad + t * 8);
    GLOAD_LDS(gA + (size_t)64 * lda + k0, Ad + (512 + t) * 8);
    GLOAD_LDS(gB + k0, Bd + t * 8);
    GLOAD_LDS(gB + (size_t)64 * K + k0, Bd + (512 + t) * 8);
  };

  int aoff[2][2], boff[4][2];
#pragma unroll
  for (int ks = 0; ks < 2; ++ks) {
#pragma unroll
    for (int i = 0; i < 2; ++i) {
      int ra = wr*32 + i*16 + lr;
      aoff[i][ks] = ra*64 + (((ks*4 + lg) ^ (ra & 7)) * 8);
    }
#pragma unroll
    for (int j = 0; j < 4; ++j) {
      int rb = wc*64 + j*16 + lr;
      boff[j][ks] = rb*64 + (((ks*4 + lg) ^ (rb & 7)) * 8);
    }
  }

  int NK = K >> 6;
  stage(0, 0);
  __syncthreads();
  for (int kt = 0; kt < NK; ++kt) {
    int cur = kt & 1;
    if (kt + 1 < NK) stage((kt + 1) << 6, cur ^ 1);  // prefetch flies under MFMA
    const __bf16* As = sm + cur * 8192;
    const __bf16* Bs = sm + 16384 + cur * 8192;
#pragma unroll
    for (int ks = 0; ks < 2; ++ks) {
      bf16x8 af[2], bfr[4];
#pragma unroll
      for (int i = 0; i < 2; ++i) af[i]  = *(const bf16x8*)(As + aoff[i][ks]);
#pragma unroll
      for (int j = 0; j < 4; ++j) bfr[j] = *(const bf16x8*)(Bs + boff[j][ks]);
      __builtin_amdgcn_s_setprio(1);
#pragma unroll
      for (int i = 0; i < 2; ++i)
#pragma unroll
        for (int j = 0; j < 4; ++j)
          acc[i][j] = mfma_bf16(af[i], bfr[j], acc[i][j]);
      __builtin_amdgcn_s_setprio(0);
    }
    __syncthreads();
  }

  if (EPI == 1) {
    int lbase = m0 & 511;
    float s1[4] = {0.f,0.f,0.f,0.f}, s2[4] = {0.f,0.f,0.f,0.f};
#pragma unroll
    for (int i = 0; i < 2; ++i)
#pragma unroll
      for (int j = 0; j < 4; ++j)
#pragma unroll
        for (int q = 0; q < 4; ++q) {
          int rrow = wr*32 + i*16 + lg*4 + q;
          int col = n0 + wc*64 + j*16 + lr;
          float v = acc[i][j][q] + bias[col];
          outQK[(size_t)(m0 + rrow) * N + col] = __float2bfloat16(v);
          if (lbase + rrow < lenb) { s1[j] += v; s2[j] += v*v; }
        }
#pragma unroll
    for (int j = 0; j < 4; ++j) {
      s1[j] += __shfl_xor(s1[j], 16); s1[j] += __shfl_xor(s1[j], 32);
      s2[j] += __shfl_xor(s2[j], 16); s2[j] += __shfl_xor(s2[j], 32);
    }
    float* fb = (float*)sm;   // [4 wr][128 cloc] x {s1,s2} = 4KB
    if (lg == 0) {
#pragma unroll
      for (int j = 0; j < 4; ++j) {
        int cloc = wc*64 + j*16 + lr;
        fb[wr*128 + cloc] = s1[j];
        fb[512 + wr*128 + cloc] = s2[j];
      }
    }
    __syncthreads();
    if (t < 128) {
      pS [by*256 + bx*128 + t] = fb[t] + fb[128 + t] + fb[256 + t] + fb[384 + t];
      pS2[by*256 + bx*128 + t] = fb[512 + t] + fb[640 + t] + fb[768 + t] + fb[896 + t];
    }
  } else if (n0 < 1024) {
#pragma unroll
    for (int i = 0; i < 2; ++i)
#pragma unroll
      for (int j = 0; j < 4; ++j)
#pragma unroll
        for (int q = 0; q < 4; ++q) {
          int row = m0 + wr*32 + i*16 + lg*4 + q;
          int col = n0 + wc*64 + j*16 + lr;
          outQK[(size_t)row * 1024 + col] = __float2bfloat16(acc[i][j][q]);
        }
  } else {
    // V region: transpose via LDS (Ct[128][136] = 34816 B), coalesced 16-B stores
    __bf16* Ct = sm;
#pragma unroll
    for (int i = 0; i < 2; ++i)
#pragma unroll
      for (int j = 0; j < 4; ++j) {
        int col = wc*64 + j*16 + lr;
        int row0 = wr*32 + i*16 + lg*4;
        bf16x4 pv;
#pragma unroll
        for (int q = 0; q < 4; ++q) pv[q] = (__bf16)acc[i][j][q];
        *(bf16x4*)(Ct + col*136 + row0) = pv;
      }
    __syncthreads();
    int b = m0 >> 9, l0 = m0 & 511, gcol0 = n0 - 1024;
#pragma unroll
    for (int it = 0; it < 4; ++it) {
      int g = it * 512 + t;
      int vv = g >> 4, rc = g & 15;
      bf16x8 val = *(const bf16x8*)(Ct + vv*136 + rc*8);
      int gc = gcol0 + vv, h = gc >> 6, vg = gc & 63;
      *(bf16x8*)((__bf16*)outVT + ((size_t)((b*HH + h)*64 + vg))*512 + l0 + rc*8) = val;
    }
  }
}

// ---------------- attention v9: LPT order, 3-buf counted vmcnt (closed load set) ----------------
__global__ __launch_bounds__(512)
void attn(__hip_bfloat16* QK, const __hip_bfloat16* __restrict__ VT,
          const int* __restrict__ lengths, const int* __restrict__ order) {
  int hw = blockIdx.x;                       // 2048 blocks
  int h = hw & 7, r = hw >> 3;
  int rank = r >> 2, qt = r & 3;
  int b = order[rank];
  int len = lengths[b];
  if (qt * 128 >= len) return;
  __shared__ __align__(16) __hip_bfloat16 Ks[3][2048];   // 32 keys x 64 d
  __shared__ __align__(16) __hip_bfloat16 Vs[3][2048];   // 64 v x 32 l
  __shared__ __align__(16) __hip_bfloat16 P[8][16][40];  // 32 keys + pad
  int t = threadIdx.x, wave = t >> 6, lane = t & 63, lr = lane & 15, lg = lane >> 4;
  int q0 = qt * 128 + wave * 16;
  const __hip_bfloat16* Qb = QK + (size_t)b*512*1024 + h*64;
  const __hip_bfloat16* Kb = QK + (size_t)b*512*1024 + 512 + h*64;
  const __hip_bfloat16* Vb = VT + (size_t)(b*HH + h)*64*512;

  bf16x8 qf0 = *(const bf16x8*)(Qb + (size_t)(q0 + lr)*1024 + lg*8);
  bf16x8 qf1 = *(const bf16x8*)(Qb + (size_t)(q0 + lr)*1024 + 32 + lg*8);
#pragma unroll
  for (int i = 0; i < 8; ++i) {
    qf0[i] = (__bf16)((float)qf0[i] * 0.18033688f);
    qf1[i] = (__bf16)((float)qf1[i] * 0.18033688f);
  }
  bf16x8 onesf;
#pragma unroll
  for (int i = 0; i < 8; ++i) onesf[i] = (__bf16)1.0f;

  int koff0[2], koff1[2];
#pragma unroll
  for (int kb = 0; kb < 2; ++kb) {
    int row = kb*16 + lr, sw = row & 7;
    koff0[kb] = row*64 + ((lg ^ sw) * 8);
    koff1[kb] = row*64 + (((lg + 4) ^ sw) * 8);
  }
  int voff[4];
#pragma unroll
  for (int vb = 0; vb < 4; ++vb) {
    int row = vb*16 + lr;
    voff[vb] = row*32 + ((lg ^ ((row >> 1) & 3)) * 8);
  }
  int ku = t & 255;
  int krow = ku >> 3, kcb = (ku & 7) ^ (krow & 7);
  const __hip_bfloat16* kgp = Kb + (size_t)krow*1024 + kcb*8;
  int vrow = ku >> 2, vcb = (ku & 3) ^ ((vrow >> 1) & 3);
  const __hip_bfloat16* vgp = Vb + (size_t)vrow*512 + vcb*8;

  int nt = (len + 31) >> 5;

  auto stage = [&](int kt, int buf) {
    if (t < 256) GLOAD_LDS(kgp + (size_t)kt*32768, &Ks[buf][ku*8]);
    else         GLOAD_LDS(vgp + kt*32,           &Vs[buf][ku*8]);
  };

  floatx4 O[4];
  floatx4 Ol = {0.f, 0.f, 0.f, 0.f};
#pragma unroll
  for (int vb = 0; vb < 4; ++vb)
#pragma unroll
    for (int i = 0; i < 4; ++i) O[vb][i] = 0.f;

  stage(0, 0);
  if (nt > 1) {
    stage(1, 1);
    asm volatile("s_waitcnt vmcnt(1)" ::: "memory");
  } else {
    asm volatile("s_waitcnt vmcnt(0)" ::: "memory");
  }
  __builtin_amdgcn_sched_barrier(0);
  __builtin_amdgcn_s_barrier();
  __builtin_amdgcn_sched_barrier(0);

  for (int kt = 0; kt < nt; ++kt) {
    int cur = kt % 3;
    if (kt + 2 < nt) stage(kt + 2, (kt + 2) % 3);
    int kb0 = kt * 32;
    const __hip_bfloat16* Kc = Ks[cur];
    const __hip_bfloat16* Vc = Vs[cur];

    floatx4 S[2];
    __builtin_amdgcn_s_setprio(1);
#pragma unroll
    for (int kb = 0; kb < 2; ++kb) {
      bf16x8 kf0 = *(const bf16x8*)(Kc + koff0[kb]);
      bf16x8 kf1 = *(const bf16x8*)(Kc + koff1[kb]);
      floatx4 s = {0.f, 0.f, 0.f, 0.f};
      s = mfma_bf16(kf0, qf0, s);
      s = mfma_bf16(kf1, qf1, s);
      S[kb] = s;
    }
    __builtin_amdgcn_s_setprio(0);
#pragma unroll
    for (int kb = 0; kb < 2; ++kb)
#pragma unroll
      for (int i = 0; i < 4; ++i) S[kb][i] = __builtin_amdgcn_exp2f(S[kb][i]);
    if (kb0 + 32 > len) {
#pragma unroll
      for (int kb = 0; kb < 2; ++kb)
#pragma unroll
        for (int i = 0; i < 4; ++i)
          if (kb0 + kb*16 + lg*4 + i >= len) S[kb][i] = 0.f;
    }
#pragma unroll
    for (int kb = 0; kb < 2; ++kb) {
      bf16x4 pv;
#pragma unroll
      for (int i = 0; i < 4; ++i) pv[i] = (__bf16)S[kb][i];
      *(bf16x4*)(&P[wave][lr][kb*16 + lg*4]) = pv;
    }
    bf16x8 pf = *(const bf16x8*)(&P[wave][lr][lg*8]);
    __builtin_amdgcn_s_setprio(1);
#pragma unroll
    for (int vb = 0; vb < 4; ++vb) {
      bf16x8 vf = *(const bf16x8*)(Vc + voff[vb]);
      O[vb] = mfma_bf16(pf, vf, O[vb]);
    }
    Ol = mfma_bf16(pf, onesf, Ol);
    __builtin_amdgcn_s_setprio(0);

    if (kt + 1 < nt) {
      if (kt + 2 < nt) asm volatile("s_waitcnt vmcnt(1)" ::: "memory");
      else             asm volatile("s_waitcnt vmcnt(0)" ::: "memory");
      __builtin_amdgcn_sched_barrier(0);
      __builtin_amdgcn_s_barrier();
      __builtin_amdgcn_sched_barrier(0);
    }
  }

#pragma unroll
  for (int vb = 0; vb < 4; ++vb)
#pragma unroll
    for (int i = 0; i < 4; ++i) {
      int q = q0 + lg*4 + i;
      float z = O[vb][i] / Ol[i];
      QK[(size_t)(b*512 + q)*1024 + h*64 + vb*16 + lr] = __float2bfloat16(z);
    }
}

// ---------------- BN finalize: 1024-thread parallel partial sum ----------------
__global__ __launch_bounds__(1024)
void stats_fin(const float* __restrict__ pS, const float* __restrict__ pS2,
               const int* __restrict__ lengths, const float* __restrict__ g,
               const float* __restrict__ be, float* __restrict__ aff) {
  __shared__ float red[2048];
  int t = threadIdx.x, col = t & 255, part = t >> 8;
  float s = 0.f, s2 = 0.f;
  for (int i = part*64; i < part*64 + 64; ++i) {
    s += pS[i*256 + col]; s2 += pS2[i*256 + col];
  }
  red[part*256 + col] = s;
  red[1024 + part*256 + col] = s2;
  __syncthreads();
  if (t < 256) {
    float cnt = 0.f;
    for (int i = 0; i < 64; ++i) cnt += (float)lengths[i];
    float fs = red[t] + red[256 + t] + red[512 + t] + red[768 + t];
    float fs2 = red[1024 + t] + red[1280 + t] + red[1536 + t] + red[1792 + t];
    float mean = fs / cnt;
    float var = fs2 / cnt - mean * mean;
    float a = g[t] * rsqrtf(var + 1e-5f);
    aff[t] = a;
    aff[256 + t] = be[t] - mean * a;
  }
}

// ---------------- BN-apply + ReLU + mask (bf16 in, row-skip) ----------------
__global__ __launch_bounds__(256)
void apply1(const __hip_bfloat16* __restrict__ Zr, const int* __restrict__ lengths,
            const float* __restrict__ aff, __hip_bfloat16* __restrict__ Zn) {
  int idx = blockIdx.x * 256 + threadIdx.x;
  int row = idx >> 6, c4 = (idx & 63) * 4;
  int b = row >> 9, l = row & 511;
  int lenb = lengths[b];
  if (l >= ((lenb + 127) & ~127)) return;    // rows never read by gemmZ2
  bool ok = l < lenb;
  bf16x4 z = *(const bf16x4*)((const __bf16*)Zr + (size_t)row*256 + c4);
  float4 a = *(const float4*)(aff + c4);
  float4 c = *(const float4*)(aff + 256 + c4);
  bf16x4 o;
  o[0] = (__bf16)(ok ? fmaxf(a.x*(float)z[0] + c.x, 0.f) : 0.f);
  o[1] = (__bf16)(ok ? fmaxf(a.y*(float)z[1] + c.y, 0.f) : 0.f);
  o[2] = (__bf16)(ok ? fmaxf(a.z*(float)z[2] + c.z, 0.f) : 0.f);
  o[3] = (__bf16)(ok ? fmaxf(a.w*(float)z[3] + c.w, 0.f) : 0.f);
  *(bf16x4*)((__bf16*)Zn + (size_t)row*256 + c4) = o;
}

__global__ __launch_bounds__(256)
void apply2(const __hip_bfloat16* __restrict__ Zr, const float* __restrict__ emb,
            const int* __restrict__ lengths, const float* __restrict__ aff,
            float* __restrict__ out) {
  int idx = blockIdx.x * 256 + threadIdx.x;
  int row = idx >> 6, c4 = (idx & 63) * 4;
  int b = row >> 9, l = row & 511;
  size_t base = (size_t)row*256 + c4;
  if (l >= lengths[b]) {                     // masked row: zeros, no loads
    float4 z = {0.f, 0.f, 0.f, 0.f};
    *(float4*)(out + base) = z;
    return;
  }
  bf16x4 zv = *(const bf16x4*)((const __bf16*)Zr + base);
  float4 e = *(const float4*)(emb + base);
  float4 a = *(const float4*)(aff + c4);
  float4 c = *(const float4*)(aff + 256 + c4);
  float4 o;
  o.x = fmaxf(a.x*(float)zv[0] + c.x + e.x, 0.f);
  o.y = fmaxf(a.y*(float)zv[1] + c.y + e.y, 0.f);
  o.z = fmaxf(a.z*(float)zv[2] + c.z + e.z, 0.f);
  o.w = fmaxf(a.w*(float)zv[3] + c.w + e.w, 0.f);
  *(float4*)(out + base) = o;
}

// ---------------- launch ----------------
extern "C" void kernel_launch(void* const* d_in, const int* in_sizes, int n_in,
                              void* d_out, int out_size, void* d_ws, size_t ws_size,
                              hipStream_t stream) {
  const float* emb   = (const float*)d_in[0];
  const float* boxes = (const float*)d_in[1];
  const int*   dlen  = (const int*)d_in[2];
  const float* Wq    = (const float*)d_in[3];
  const float* Wk    = (const float*)d_in[4];
  const float* Wv    = (const float*)d_in[5];
  const float* W1    = (const float*)d_in[6];
  const float* b1    = (const float*)d_in[7];
  const float* W2    = (const float*)d_in[8];
  const float* b2    = (const float*)d_in[9];
  const float* g1    = (const float*)d_in[10];
  const float* be1   = (const float*)d_in[11];
  const float* g2    = (const float*)d_in[12];
  const float* be2   = (const float*)d_in[13];
  float* out = (float*)d_out;

  // ws layout (bytes)
  const size_t oWqkvT = 0;          // 1536*320*2  = 983040
  const size_t oW1T   = 983040;     // 256*512*2   = 262144
  const size_t oW2T   = 1245184;    // 256*256*2   = 131072
  const size_t oAff1  = 1376256;    // 2048
  const size_t oAff2  = 1378304;    // 2048
  const size_t oPS    = 1380352;    // 256*256*4 = 262144
  const size_t oPS2   = 1642496;    // 262144
  const size_t oXbf   = 1904640;    // 32768*320*2 = 20971520 (reused by Z1n)
  const size_t oQK    = 22876160;   // 32768*1024*2= 67108864 (Z in-place; reused by Z2b)
  const size_t oVT    = 89985024;   // 8*64*64*512*2 = 33554432 (reused by Z1b)
  const size_t oOrd   = 123539456;  // 256
  const size_t NEED   = 123539712;
  if (ws_size < NEED) { fprintf(stderr, "ws too small: %zu < %zu\n", ws_size, NEED); return; }

  char* w = (char*)d_ws;
  __hip_bfloat16* WqkvT = (__hip_bfloat16*)(w + oWqkvT);
  __hip_bfloat16* W1T   = (__hip_bfloat16*)(w + oW1T);
  __hip_bfloat16* W2T   = (__hip_bfloat16*)(w + oW2T);
  float* aff1 = (float*)(w + oAff1);
  float* aff2 = (float*)(w + oAff2);
  float* pS   = (float*)(w + oPS);
  float* pS2  = (float*)(w + oPS2);
  __hip_bfloat16* Xbf = (__hip_bfloat16*)(w + oXbf);
  __hip_bfloat16* Z1n = (__hip_bfloat16*)(w + oXbf);
  __hip_bfloat16* QK  = (__hip_bfloat16*)(w + oQK);
  __hip_bfloat16* Z2b = (__hip_bfloat16*)(w + oQK);
  __hip_bfloat16* VT  = (__hip_bfloat16*)(w + oVT);
  __hip_bfloat16* Z1b = (__hip_bfloat16*)(w + oVT);
  int* order = (int*)(w + oOrd);

  prep_all<<<1 + 168 + ROWS/4 + ROWS/16, 256, 0, stream>>>(
      emb, boxes, Xbf, Wq, Wk, Wv, W1, W2, WqkvT, W1T, W2T, dlen, order);
  // QKV projection: [32768,320] x [320,1536], grid 12x256 XCD-chunked, LPT + M-sparse
  gemm_bt<0><<<12*256, 512, 0, stream>>>(
      Xbf, WqkvT, 12, NQKV, DD, DD, nullptr, QK, VT,
      dlen, order, nullptr, nullptr);
  attn<<<2048, 512, 0, stream>>>(QK, VT, dlen, order);
  // Z @ W1 + b1 (Z lives in QK cols 0..511, lda=1024), bf16 out + fused stats
  gemm_bt<1><<<2*256, 512, 0, stream>>>(
      QK, W1T, 2, 256, 512, 1024, b1, Z1b, nullptr,
      dlen, order, pS, pS2);
  stats_fin<<<1, 1024, 0, stream>>>(pS, pS2, dlen, g1, be1, aff1);
  apply1<<<ROWS/4, 256, 0, stream>>>(Z1b, dlen, aff1, Z1n);
  // Z1n @ W2 + b2, bf16 out + fused stats
  gemm_bt<1><<<2*256, 512, 0, stream>>>(
      Z1n, W2T, 2, 256, 256, 256, b2, Z2b, nullptr,
      dlen, order, pS, pS2);
  stats_fin<<<1, 1024, 0, stream>>>(pS, pS2, dlen, g2, be2, aff2);
  apply2<<<ROWS/4, 256, 0, stream>>>(Z2b, emb, dlen, aff2, out);
}